// Round 10
// baseline (650.961 us; speedup 1.0000x reference)
//
#include <hip/hip_runtime.h>
#include <hip/hip_bf16.h>

// Closed-loop NARX on MI355X.
// 128 blocks x 512 threads (8 waves); each block owns 16 batch rows for all
// 504 steps. Register-resident: W1 frags, W2 K-slice, 8-slot x window, AND
// the 8-slot y history (parity scheme: chunk c of lane-group g holds history
// i = 2c + (g ^ t&1); window slide needs only a per-lane cndmask shift on
// alternating groups + one b128 LDS read of the newest y per wave; the
// weight pairing alternates between wf[8+c] and wfo[c] = same W1 columns
// with lg-group k-offsets swapped). LDS carries only: newest-y handoff,
// per-wave packed h tile, f32 layer-2 partials.

typedef short bf16x8 __attribute__((ext_vector_type(8)));  // 8 bf16 bit patterns
typedef float f32x4  __attribute__((ext_vector_type(4)));

#define MFMA16(A,B,C) __builtin_amdgcn_mfma_f32_16x16x32_bf16((A),(B),(C),0,0,0)

constexpr int DT = 512;              // T
constexpr int DX = 32;               // d_x
constexpr int DY = 16;               // d_y
constexpr int BB = 16;               // batch rows per block

// LDS strides
constexpr int YROW  = 24;            // shorts per y row (48 B)
constexpr int YSLOT = 16 * YROW;
constexpr int H32ROW = 20;           // u32 per packed-h row (80 B, 16B-mult)
constexpr int H32WAVE = 16 * H32ROW; // 320 u32 per wave
constexpr int PROW  = 18;            // f32 partial row stride (stores 2-way free)
constexpr int PWAVE = 16 * PROW;

__device__ __forceinline__ short bfbits(float f) {
  return __builtin_bit_cast(short, (__bf16)f);   // hardware RNE convert
}
__device__ __forceinline__ float fast_tanh(float a) {
  float e = __expf(2.0f * a);                    // stable both tails
  return 1.0f - 2.0f * __builtin_amdgcn_rcpf(e + 1.0f);
}
__device__ __forceinline__ float fast_sigmoid(float a) {
  return __builtin_amdgcn_rcpf(1.0f + __expf(-a));
}

__global__ __launch_bounds__(512, 2) void narx_kernel(
    const float* __restrict__ x,  const float* __restrict__ W1,
    const float* __restrict__ b1, const float* __restrict__ W2,
    const float* __restrict__ b2, float* __restrict__ out)
{
  __shared__ __align__(16) short ybuf[8 * YSLOT];        //  6144 B
  __shared__ __align__(16) unsigned int hbuf32[8 * H32WAVE]; // 10240 B
  __shared__ __align__(16) float pbuf[8 * PWAVE];        //  9216 B

  const int tid  = threadIdx.x;
  const int lane = tid & 63;
  const int w    = tid >> 6;        // wave 0..7 -> hidden cols [w*32, w*32+32)
  const int lm   = lane & 15;
  const int lg   = lane >> 4;       // 0..3
  const int b0   = blockIdx.x * BB;

  // ---- W1 fragments: lane holds W1[n=base+lm][k = c*32 + lg*8 .. +7] ----
  bf16x8 wf[2][12];
#pragma unroll
  for (int ti = 0; ti < 2; ++ti) {
    const int n = w * 32 + ti * 16 + lm;
#pragma unroll
    for (int c = 0; c < 12; ++c) {
      const float* p = W1 + n * 384 + c * 32 + lg * 8;
      bf16x8 v;
#pragma unroll
      for (int j = 0; j < 8; ++j) v[j] = bfbits(p[j]);
      wf[ti][c] = v;
    }
  }
  // odd-parity history weights: same W1 history cols, lg-group k-offset swapped
  bf16x8 wfo[2][4];
#pragma unroll
  for (int ti = 0; ti < 2; ++ti) {
    const int n = w * 32 + ti * 16 + lm;
#pragma unroll
    for (int c = 0; c < 4; ++c) {
      const float* p = W1 + n * 384 + 256 + c * 32 + (lg ^ 2) * 8;
      bf16x8 v;
#pragma unroll
      for (int j = 0; j < 8; ++j) v[j] = bfbits(p[j]);
      wfo[ti][c] = v;
    }
  }
  // W2 K-slice with the packed-h column permutation folded in:
  // storage pos p holds h col (p&1) ? 16+(p>>1) : (p>>1)
  bf16x8 w2fp;
#pragma unroll
  for (int j = 0; j < 8; ++j) {
    const int p = lg * 8 + j;
    const int col = (p & 1) ? (16 + (p >> 1)) : (p >> 1);
    w2fp[j] = bfbits(W2[lm * 256 + w * 32 + col]);
  }
  const float b1v0 = b1[w * 32 + lm];
  const float b1v1 = b1[w * 32 + 16 + lm];
  const float b2v  = b2[lm];

  // ---- zero out[:, 0:8, :] for this block's rows (d_out is poisoned) ----
  {
    const int m = tid >> 5, off = (tid & 31) * 4;   // 128 floats per row prefix
    f32x4 z = {0.f, 0.f, 0.f, 0.f};
    *reinterpret_cast<f32x4*>(out + (size_t)(b0 + m) * (DT * DY) + off) = z;
  }

  // ---- register-resident x window: slot s holds x[tau], tau%8 == s ----
  const float* xlane = x + (size_t)(b0 + lm) * (DT * DX) + lg * 8;
  bf16x8 xr[8];
#pragma unroll
  for (int s = 0; s < 8; ++s) {
    f32x4 a = *reinterpret_cast<const f32x4*>(xlane + s * DX);
    f32x4 b = *reinterpret_cast<const f32x4*>(xlane + s * DX + 4);
    bf16x8 v;
#pragma unroll
    for (int j = 0; j < 4; ++j) { v[j] = bfbits(a[j]); v[4 + j] = bfbits(b[j]); }
    xr[s] = v;
  }
  // prefetch x[8]
  f32x4 gA0 = *reinterpret_cast<const f32x4*>(xlane + 8 * DX);
  f32x4 gA1 = *reinterpret_cast<const f32x4*>(xlane + 8 * DX + 4);
  f32x4 gB0 = gA0, gB1 = gA1;

  // register y history (all zeros initially; history i = 2c + (lg>>1 ^ t&1))
  bf16x8 yr0 = {0,0,0,0,0,0,0,0}, yr1 = {0,0,0,0,0,0,0,0};
  bf16x8 yr2 = {0,0,0,0,0,0,0,0}, yr3 = {0,0,0,0,0,0,0,0};

  // zero ybuf (slot 7 is read as "y[7]"=0 by the first dummy shift)
  for (int i = tid; i < 8 * YSLOT; i += 512) ybuf[i] = 0;
  __syncthreads();

  // lane constants
  const int g      = lg >> 1;
  const int yfoff  = lm * YROW + (lg & 1) * 8;      // fresh-y read offset
  const int hw32   = w * H32WAVE;
  const int hread  = hw32 + lm * H32ROW + lg * 4;   // u32 idx; byte lm*80+lg*16
  const int pw     = w * PWAVE;
  const int rrow   = tid >> 4, rcol = tid & 15;     // reduce thread mapping

#define STEP(U, CUR0, CUR1, NXT0, NXT1)                                        \
  do {                                                                         \
    const int t = tb + (U);                                                    \
    { const int tl = (t + 1 < DT) ? (t + 1) : (DT - 1);                        \
      NXT0 = *reinterpret_cast<const f32x4*>(xlane + tl * DX);                 \
      NXT1 = *reinterpret_cast<const f32x4*>(xlane + tl * DX + 4); }           \
    /* y-window slide: group ((U)+1)&1 shifts chunks down, takes y[t-1] */     \
    { bf16x8 fresh = *reinterpret_cast<const bf16x8*>(                         \
          &ybuf[(((U) + 7) & 7) * YSLOT + yfoff]);                             \
      const bool ds_ = (g == (((U) + 1) & 1));                                 \
      yr0 = ds_ ? yr1 : yr0;                                                   \
      yr1 = ds_ ? yr2 : yr1;                                                   \
      yr2 = ds_ ? yr3 : yr2;                                                   \
      yr3 = ds_ ? fresh : yr3; }                                               \
    /* layer 1: inp[16,384] @ W1^T (wave owns 32 hidden cols) */               \
    f32x4 acc0a = {0.f,0.f,0.f,0.f}, acc0b = {0.f,0.f,0.f,0.f};                \
    f32x4 acc1a = {0.f,0.f,0.f,0.f}, acc1b = {0.f,0.f,0.f,0.f};                \
    _Pragma("unroll") for (int c = 0; c < 6; ++c) {                            \
      acc0a = MFMA16(xr[((U) + c) & 7], wf[0][c], acc0a);                      \
      acc1a = MFMA16(xr[((U) + c) & 7], wf[1][c], acc1a);                      \
    }                                                                          \
    acc0b = MFMA16(xr[((U) + 6) & 7], wf[0][6], acc0b);                        \
    acc1b = MFMA16(xr[((U) + 6) & 7], wf[1][6], acc1b);                        \
    acc0b = MFMA16(xr[((U) + 7) & 7], wf[0][7], acc0b);                        \
    acc1b = MFMA16(xr[((U) + 7) & 7], wf[1][7], acc1b);                        \
    if ((U) & 1) {   /* odd t: history i = 2c + (g^1) -> swapped weights */    \
      acc0b = MFMA16(yr0, wfo[0][0], acc0b); acc1b = MFMA16(yr0, wfo[1][0], acc1b); \
      acc0b = MFMA16(yr1, wfo[0][1], acc0b); acc1b = MFMA16(yr1, wfo[1][1], acc1b); \
      acc0b = MFMA16(yr2, wfo[0][2], acc0b); acc1b = MFMA16(yr2, wfo[1][2], acc1b); \
      acc0b = MFMA16(yr3, wfo[0][3], acc0b); acc1b = MFMA16(yr3, wfo[1][3], acc1b); \
    } else {         /* even t: history i = 2c + g -> normal weights */        \
      acc0b = MFMA16(yr0, wf[0][8],  acc0b); acc1b = MFMA16(yr0, wf[1][8],  acc1b); \
      acc0b = MFMA16(yr1, wf[0][9],  acc0b); acc1b = MFMA16(yr1, wf[1][9],  acc1b); \
      acc0b = MFMA16(yr2, wf[0][10], acc0b); acc1b = MFMA16(yr2, wf[1][10], acc1b); \
      acc0b = MFMA16(yr3, wf[0][11], acc0b); acc1b = MFMA16(yr3, wf[1][11], acc1b); \
    }                                                                          \
    /* install x[t] into slot (U)&7 (prefetched last step) */                  \
    { bf16x8 nx;                                                               \
      _Pragma("unroll") for (int j = 0; j < 4; ++j) {                          \
        nx[j] = bfbits(CUR0[j]); nx[4 + j] = bfbits(CUR1[j]); }                \
      xr[(U) & 7] = nx; }                                                      \
    /* tanh + packed h store: u32 = (col lm | col 16+lm) at pos 2lm,2lm+1 */   \
    _Pragma("unroll") for (int r = 0; r < 4; ++r) {                            \
      const int row = lg * 4 + r;                                              \
      const float h0 = fast_tanh(acc0a[r] + acc0b[r] + b1v0);                  \
      const float h1 = fast_tanh(acc1a[r] + acc1b[r] + b1v1);                  \
      const unsigned int hp = (unsigned int)(unsigned short)bfbits(h0)         \
                            | ((unsigned int)(unsigned short)bfbits(h1) << 16);\
      hbuf32[hw32 + row * H32ROW + lm] = hp;                                   \
    }                                                                          \
    /* layer 2, K-split: 1 MFMA per wave over its own (permuted) 32 cols */    \
    bf16x8 ha = *reinterpret_cast<const bf16x8*>(&hbuf32[hread]);              \
    f32x4 pz = {0.f, 0.f, 0.f, 0.f};                                           \
    f32x4 part = MFMA16(ha, w2fp, pz);                                         \
    _Pragma("unroll") for (int r = 0; r < 4; ++r)                              \
      pbuf[pw + (lg * 4 + r) * PROW + lm] = part[r];                           \
    __syncthreads();                                                           \
    if (tid < 256) {                                                           \
      float s = b2v;                                                           \
      _Pragma("unroll") for (int ww = 0; ww < 8; ++ww)                         \
        s += pbuf[ww * PWAVE + rrow * PROW + rcol];                            \
      const float o = fast_sigmoid(s);                                         \
      ybuf[((U) & 7) * YSLOT + rrow * YROW + rcol] = bfbits(o);                \
      out[(size_t)(b0 + rrow) * (DT * DY) + t * DY + rcol] = o;                \
    }                                                                          \
    __syncthreads();                                                           \
  } while (0)

  for (int tb = 8; tb < DT; tb += 8) {   // 504 steps = 63 x 8; U parity static
    STEP(0, gA0, gA1, gB0, gB1);
    STEP(1, gB0, gB1, gA0, gA1);
    STEP(2, gA0, gA1, gB0, gB1);
    STEP(3, gB0, gB1, gA0, gA1);
    STEP(4, gA0, gA1, gB0, gB1);
    STEP(5, gB0, gB1, gA0, gA1);
    STEP(6, gA0, gA1, gB0, gB1);
    STEP(7, gB0, gB1, gA0, gA1);
  }
#undef STEP
}

extern "C" void kernel_launch(void* const* d_in, const int* in_sizes, int n_in,
                              void* d_out, int out_size, void* d_ws, size_t ws_size,
                              hipStream_t stream) {
  const float* x  = (const float*)d_in[0];
  const float* W1 = (const float*)d_in[1];
  const float* b1 = (const float*)d_in[2];
  const float* W2 = (const float*)d_in[3];
  const float* b2 = (const float*)d_in[4];
  float* out = (float*)d_out;
  narx_kernel<<<dim3(128), dim3(512), 0, stream>>>(x, W1, b1, W2, b2, out);
}